// Round 6
// baseline (248.790 us; speedup 1.0000x reference)
//
#include <hip/hip_runtime.h>

#define S_LEN 2048
#define DMODEL 768
#define NH 12
#define DHEAD 64
#define BATCH 4
#define MROWS (BATCH * S_LEN)  // 8192
#define NQKV 2304              // 3*DMODEL
#define LOG2E 1.44269504088896340736f

using short8 = __attribute__((ext_vector_type(8))) short;
using f32x4  = __attribute__((ext_vector_type(4))) float;
using f32x16 = __attribute__((ext_vector_type(16))) float;

typedef const __attribute__((address_space(1))) void* gas_ptr;
typedef __attribute__((address_space(3))) void* las_ptr;

__device__ __forceinline__ void gl2lds16(const void* g, void* l) {
  __builtin_amdgcn_global_load_lds((gas_ptr)(unsigned long long)g,
                                   (las_ptr)(unsigned int)(unsigned long long)l,
                                   16, 0, 0);
}

__device__ inline unsigned short f2bf(float f) {
  union { float f; unsigned int u; } c; c.f = f;
  unsigned int u = c.u;
  unsigned int r = (u + 0x7FFFu + ((u >> 16) & 1u)) >> 16;
  return (unsigned short)r;
}

__device__ inline unsigned int pack2bf(float a, float b) {
  union { float f; unsigned int u; } ca, cb;
  ca.f = a; cb.f = b;
  unsigned int ua = ca.u, ub = cb.u;
  ua = (ua + 0x7FFFu + ((ua >> 16) & 1u)) >> 16;
  ub = (ub + 0x7FFFu + ((ub >> 16) & 1u)) & 0xFFFF0000u;
  return ua | ub;
}

// Fused prep: fp32->bf16 for X and the 3 W's, mask -> (mask-10)*log2e
__global__ __launch_bounds__(256) void prep_kernel(
    const float* __restrict__ hs, const float* __restrict__ Wq,
    const float* __restrict__ Wk, const float* __restrict__ Wv,
    const float* __restrict__ mask,
    unsigned short* __restrict__ Xb, unsigned short* __restrict__ Wall,
    float* __restrict__ mask2)
{
  const int NX = MROWS * DMODEL / 4;
  const int NW = DMODEL * DMODEL / 4;
  const int NM = (BATCH * S_LEN) / 4;
  int i = blockIdx.x * 256 + threadIdx.x;
  if (i < NX) {
    float4 f = ((const float4*)hs)[i];
    ushort4 o = { f2bf(f.x), f2bf(f.y), f2bf(f.z), f2bf(f.w) };
    ((ushort4*)Xb)[i] = o;
  } else if (i < NX + 3 * NW) {
    int j = i - NX;
    int sec = j / NW, r = j - sec * NW;
    const float* src = (sec == 0) ? Wq : (sec == 1) ? Wk : Wv;
    float4 f = ((const float4*)src)[r];
    ushort4 o = { f2bf(f.x), f2bf(f.y), f2bf(f.z), f2bf(f.w) };
    ((ushort4*)(Wall + (size_t)sec * DMODEL * DMODEL))[r] = o;
  } else if (i < NX + 3 * NW + NM) {
    int r = i - NX - 3 * NW;
    float4 m = ((const float4*)mask)[r];
    float4 o = { (m.x - 10.f) * LOG2E, (m.y - 10.f) * LOG2E,
                 (m.z - 10.f) * LOG2E, (m.w - 10.f) * LOG2E };
    ((float4*)mask2)[r] = o;
  }
}

// Out[m,n] = sum_k X[m,k]*Wall[n,k] + bias(n); Q section pre-scaled by log2e/8.
__global__ __launch_bounds__(256) void qkv_gemm(
    const unsigned short* __restrict__ Xb,   // [8192][768]
    const unsigned short* __restrict__ Wall, // [2304][768]
    const float* __restrict__ bq,
    const float* __restrict__ bk,
    const float* __restrict__ bv,
    unsigned short* __restrict__ Out)        // [8192][2304]
{
  __shared__ __align__(16) short As[128][64];
  __shared__ __align__(16) short Bs[128][64];

  int m0 = blockIdx.y * 128;
  int n0 = blockIdx.x * 128;
  int t = threadIdx.x;
  int w = t >> 6, lane = t & 63, lg = lane >> 4, lc = lane & 15;
  int wr = (w >> 1) * 64, wc = (w & 1) * 64;

  int srow = lane >> 3;
  int schunk = (lane & 7) ^ srow;

  f32x4 acc[4][4] = {};

  for (int k0 = 0; k0 < DMODEL; k0 += 64) {
    __syncthreads();
    for (int it = 0; it < 4; ++it) {
      int rb = w * 32 + it * 8;
      int r = rb + srow;
      gl2lds16(&Xb[(size_t)(m0 + r) * DMODEL + k0 + schunk * 8], &As[rb][0]);
      gl2lds16(&Wall[(size_t)(n0 + r) * DMODEL + k0 + schunk * 8], &Bs[rb][0]);
    }
    __syncthreads();
    for (int ks = 0; ks < 2; ++ks) {
      short8 a[4], b[4];
      for (int mt = 0; mt < 4; ++mt)
        a[mt] = *(const short8*)&As[wr + mt * 16 + lc][(((ks * 4 + lg) ^ (lc & 7))) * 8];
      for (int nt = 0; nt < 4; ++nt)
        b[nt] = *(const short8*)&Bs[wc + nt * 16 + lc][(((ks * 4 + lg) ^ (lc & 7))) * 8];
      for (int mt = 0; mt < 4; ++mt)
        for (int nt = 0; nt < 4; ++nt)
          acc[mt][nt] = __builtin_amdgcn_mfma_f32_16x16x32_bf16(a[mt], b[nt], acc[mt][nt], 0, 0, 0);
    }
  }

  for (int nt = 0; nt < 4; ++nt) {
    int col = n0 + wc + nt * 16 + lc;
    float bb = (col < 768) ? bq[col] : (col < 1536) ? bk[col - 768] : bv[col - 1536];
    float sc = (col < 768) ? (0.125f * LOG2E) : 1.0f;
    for (int mt = 0; mt < 4; ++mt) {
      int row = m0 + wr + mt * 16 + lg * 4;
      for (int i = 0; i < 4; ++i)
        Out[(size_t)(row + i) * NQKV + col] = f2bf((acc[mt][nt][i] + bb) * sc);
    }
  }
}

// V section of QKV -> Vt [b][h][d][s]
__global__ __launch_bounds__(256) void v_transpose(
    const unsigned short* __restrict__ QKV,
    unsigned short* __restrict__ Vt)
{
  int st = blockIdx.x, h = blockIdx.y, b = blockIdx.z;
  __shared__ __align__(16) short Ls[64][72];
  int t = threadIdx.x;
  int s0 = st * 64;
  int lr = t >> 3, ls = (t & 7) * 8;
  for (int it = 0; it < 2; ++it) {
    int r = lr + it * 32;
    *(int4*)&Ls[r][ls] =
        *(const int4*)&QKV[(size_t)(b * S_LEN + s0 + r) * NQKV + 1536 + h * DHEAD + ls];
  }
  __syncthreads();
  int d = t & 63, sq = t >> 6;
  size_t obase = ((size_t)((b * NH + h) * DHEAD + d)) * S_LEN + s0;
  for (int it = 0; it < 2; ++it) {
    int ss = sq + it * 4;
    short8 vv;
    for (int j = 0; j < 8; ++j) vv[j] = Ls[ss * 8 + j][d];
    *(short8*)&Vt[obase + ss * 8] = vv;
  }
}

// Flash attention: 32x32x16 MFMA, fixed-max softmax (exp2 domain), shfl-based
// P layout transform (no LDS round-trip), double-buffered K/V, 1 barrier/iter.
// Block = (128 q, h, b); 4 waves x 32 q.
__global__ __launch_bounds__(256, 3) void flash_attn(
    const unsigned short* __restrict__ QKV,  // [8192][2304]; Q pre-scaled log2e/8
    const unsigned short* __restrict__ Vt,   // [48*64][2048]
    const float* __restrict__ mask2,         // (mask-10)*log2e, [B][S]
    float* __restrict__ out)                 // [B][S][768]
{
  int qt = blockIdx.x, h = blockIdx.y, b = blockIdx.z;
  __shared__ __align__(16) short Ks[2][64][64];   // swizzled [key][d]
  __shared__ __align__(16) short Vts[2][64][64];  // swizzled [d][key]

  int t = threadIdx.x, w = t >> 6, lane = t & 63;
  int m31 = lane & 31, hf = lane >> 5;
  int q0 = qt * 128;
  int srow = lane >> 3;
  int schunk = (lane & 7) ^ srow;

  size_t vtbase = (size_t)((b * NH + h) * DHEAD) * S_LEN;
  const float* mrow = mask2 + (size_t)b * S_LEN;
  size_t kbase0 = (size_t)(b * S_LEN) * NQKV + 768 + h * DHEAD;

  // Q B-frags: loop-invariant, direct from global. B[n=q=m31][k=d=16kk+8hf+j]
  short8 qf[4];
  {
    size_t qrow = (size_t)(b * S_LEN + q0 + w * 32 + m31) * NQKV + h * DHEAD;
    for (int kk = 0; kk < 4; ++kk)
      qf[kk] = *(const short8*)&QKV[qrow + kk * 16 + hf * 8];
  }

  // prolog: stage tile 0 into buffer 0
  {
    for (int it = 0; it < 2; ++it) {
      int rb = w * 16 + it * 8;
      int r = rb + srow;
      gl2lds16(&QKV[kbase0 + (size_t)r * NQKV + schunk * 8], &Ks[0][rb][0]);
      gl2lds16(&Vt[vtbase + (size_t)r * S_LEN + schunk * 8], &Vts[0][rb][0]);
    }
  }

  float lsum = 0.f;
  f32x16 o[2] = {};

  for (int kt = 0; kt < S_LEN / 64; ++kt) {
    int cur = kt & 1;
    int k0 = kt * 64;
    // drains this wave's DMA for tile kt (issued one full iter ago);
    // guarantees all waves done reading buf[1-cur] (tile kt-1)
    __syncthreads();

    // read all frags for this tile up-front (before next DMA issue)
    short8 kf[8], vf[8];
    for (int kk = 0; kk < 4; ++kk)
      for (int mt = 0; mt < 2; ++mt) {
        int r = mt * 32 + m31;
        int c = ((kk * 2 + hf) ^ (r & 7)) * 8;
        kf[kk * 2 + mt] = *(const short8*)&Ks[cur][r][c];
        vf[kk * 2 + mt] = *(const short8*)&Vts[cur][r][c];
      }

    // prefetch tile kt+1 into the other buffer; overlaps all compute below
    if (kt + 1 < S_LEN / 64) {
      int k1 = k0 + 64;
      for (int it = 0; it < 2; ++it) {
        int rb = w * 16 + it * 8;
        int r = rb + srow;
        gl2lds16(&QKV[kbase0 + (size_t)(k1 + r) * NQKV + schunk * 8], &Ks[cur ^ 1][rb][0]);
        gl2lds16(&Vt[vtbase + (size_t)r * S_LEN + k1 + schunk * 8], &Vts[cur ^ 1][rb][0]);
      }
    }

    // S^T[key][q] = K·Q^T: A = K rows (key tiles mt), B = qf; k-dim = d
    f32x16 s[2] = {};
    for (int kk = 0; kk < 4; ++kk)
      for (int mt = 0; mt < 2; ++mt)
        s[mt] = __builtin_amdgcn_mfma_f32_32x32x16_bf16(kf[kk * 2 + mt], qf[kk], s[mt], 0, 0, 0);

    // p = exp2(s + mask2); key = 32mt + 8g + 4hf + (r&3); q = m31
    unsigned int pk[16], xk[16];
    for (int mt = 0; mt < 2; ++mt)
      for (int g = 0; g < 4; ++g) {
        float4 mv = *(const float4*)&mrow[k0 + mt * 32 + g * 8 + hf * 4];
        float p0 = exp2f(s[mt][g * 4 + 0] + mv.x);
        float p1 = exp2f(s[mt][g * 4 + 1] + mv.y);
        float p2 = exp2f(s[mt][g * 4 + 2] + mv.z);
        float p3 = exp2f(s[mt][g * 4 + 3] + mv.w);
        lsum += (p0 + p1) + (p2 + p3);
        pk[mt * 8 + g * 2 + 0] = pack2bf(p0, p1);
        pk[mt * 8 + g * 2 + 1] = pack2bf(p2, p3);
      }

    // exchange halves with xor-32 partner (crossbar, no LDS memory)
    for (int i = 0; i < 16; ++i)
      xk[i] = (unsigned int)__shfl_xor((int)pk[i], 32, 64);

    // build P A-frags: A[m=q=m31][k=key=16kk+8hf+j], then PV
    for (int kk = 0; kk < 4; ++kk) {
      int base = (kk >> 1) * 8 + (kk & 1) * 4;
      union { unsigned int u[4]; short8 s8; } af;
      af.u[0] = hf ? xk[base + 2] : pk[base + 0];
      af.u[1] = hf ? xk[base + 3] : pk[base + 1];
      af.u[2] = hf ? pk[base + 2] : xk[base + 0];
      af.u[3] = hf ? pk[base + 3] : xk[base + 1];
      for (int nt = 0; nt < 2; ++nt)
        o[nt] = __builtin_amdgcn_mfma_f32_32x32x16_bf16(af.s8, vf[kk * 2 + nt], o[nt], 0, 0, 0);
    }
  }

  // final l for q=m31: own half + partner half
  lsum += __shfl_xor(lsum, 32, 64);
  float inv = 1.0f / lsum;
  float lv[16];
  for (int r = 0; r < 16; ++r)
    lv[r] = __shfl(inv, (r & 3) + 8 * (r >> 2) + 4 * hf, 64);

  for (int nt = 0; nt < 2; ++nt)
    for (int r = 0; r < 16; ++r) {
      int qrow = (r & 3) + 8 * (r >> 2) + 4 * hf;
      int q = q0 + w * 32 + qrow;
      out[(size_t)(b * S_LEN + q) * DMODEL + h * DHEAD + nt * 32 + m31] = o[nt][r] * lv[r];
    }
}

extern "C" void kernel_launch(void* const* d_in, const int* in_sizes, int n_in,
                              void* d_out, int out_size, void* d_ws, size_t ws_size,
                              hipStream_t stream) {
  const float* hs   = (const float*)d_in[0];
  const float* mask = (const float*)d_in[1];
  const float* Wq   = (const float*)d_in[2];
  const float* bq   = (const float*)d_in[3];
  const float* Wk   = (const float*)d_in[4];
  const float* bk   = (const float*)d_in[5];
  const float* Wv   = (const float*)d_in[6];
  const float* bv   = (const float*)d_in[7];
  float* out = (float*)d_out;

  char* ws = (char*)d_ws;
  const size_t XB_BYTES   = (size_t)MROWS * DMODEL * 2;
  const size_t QKV_BYTES  = (size_t)MROWS * NQKV * 2;
  const size_t WALL_BYTES = (size_t)NQKV * DMODEL * 2;
  unsigned short* Xb    = (unsigned short*)ws;
  unsigned short* QKV   = (unsigned short*)(ws + XB_BYTES);
  unsigned short* Wall  = (unsigned short*)(ws + XB_BYTES + QKV_BYTES);
  float*          mask2 = (float*)(ws + XB_BYTES + QKV_BYTES + WALL_BYTES);
  unsigned short* Vtg   = Xb;  // Xb dead after qkv_gemm

  const int NX = MROWS * DMODEL / 4;
  const int NW = DMODEL * DMODEL / 4;
  const int NM = (BATCH * S_LEN) / 4;
  int nprep = NX + 3 * NW + NM;
  prep_kernel<<<(nprep + 255) / 256, 256, 0, stream>>>(hs, Wq, Wk, Wv, mask, Xb, Wall, mask2);

  qkv_gemm<<<dim3(NQKV / 128, MROWS / 128), 256, 0, stream>>>(Xb, Wall, bq, bk, bv, QKV);

  v_transpose<<<dim3(S_LEN / 64, NH, BATCH), 256, 0, stream>>>(QKV, Vtg);

  flash_attn<<<dim3(S_LEN / 128, NH, BATCH), 256, 0, stream>>>(QKV, Vtg, mask2, out);
}

// Round 7
// 239.919 us; speedup vs baseline: 1.0370x; 1.0370x over previous
//
#include <hip/hip_runtime.h>

#define S_LEN 2048
#define DMODEL 768
#define NH 12
#define DHEAD 64
#define BATCH 4
#define MROWS (BATCH * S_LEN)  // 8192
#define NQK 1536               // Q+K columns only
#define LOG2E 1.44269504088896340736f

using short8 = __attribute__((ext_vector_type(8))) short;
using f32x4  = __attribute__((ext_vector_type(4))) float;
using f32x16 = __attribute__((ext_vector_type(16))) float;

typedef const __attribute__((address_space(1))) void* gas_ptr;
typedef __attribute__((address_space(3))) void* las_ptr;

__device__ __forceinline__ void gl2lds16(const void* g, void* l) {
  __builtin_amdgcn_global_load_lds((gas_ptr)(unsigned long long)g,
                                   (las_ptr)(unsigned int)(unsigned long long)l,
                                   16, 0, 0);
}

__device__ inline unsigned short f2bf(float f) {
  union { float f; unsigned int u; } c; c.f = f;
  unsigned int u = c.u;
  unsigned int r = (u + 0x7FFFu + ((u >> 16) & 1u)) >> 16;
  return (unsigned short)r;
}

__device__ inline unsigned int pack2bf(float a, float b) {
  union { float f; unsigned int u; } ca, cb;
  ca.f = a; cb.f = b;
  unsigned int ua = ca.u, ub = cb.u;
  ua = (ua + 0x7FFFu + ((ua >> 16) & 1u)) >> 16;
  ub = (ub + 0x7FFFu + ((ub >> 16) & 1u)) & 0xFFFF0000u;
  return ua | ub;
}

// Fused prep: fp32->bf16 for X and the 3 W's, mask -> (mask-10)*log2e
__global__ __launch_bounds__(256) void prep_kernel(
    const float* __restrict__ hs, const float* __restrict__ Wq,
    const float* __restrict__ Wk, const float* __restrict__ Wv,
    const float* __restrict__ mask,
    unsigned short* __restrict__ Xb, unsigned short* __restrict__ Wall,
    float* __restrict__ mask2)
{
  const int NX = MROWS * DMODEL / 4;
  const int NW = DMODEL * DMODEL / 4;
  const int NM = (BATCH * S_LEN) / 4;
  int i = blockIdx.x * 256 + threadIdx.x;
  if (i < NX) {
    float4 f = ((const float4*)hs)[i];
    ushort4 o = { f2bf(f.x), f2bf(f.y), f2bf(f.z), f2bf(f.w) };
    ((ushort4*)Xb)[i] = o;
  } else if (i < NX + 3 * NW) {
    int j = i - NX;
    int sec = j / NW, r = j - sec * NW;
    const float* src = (sec == 0) ? Wq : (sec == 1) ? Wk : Wv;
    float4 f = ((const float4*)src)[r];
    ushort4 o = { f2bf(f.x), f2bf(f.y), f2bf(f.z), f2bf(f.w) };
    ((ushort4*)(Wall + (size_t)sec * DMODEL * DMODEL))[r] = o;
  } else if (i < NX + 3 * NW + NM) {
    int r = i - NX - 3 * NW;
    float4 m = ((const float4*)mask)[r];
    float4 o = { (m.x - 10.f) * LOG2E, (m.y - 10.f) * LOG2E,
                 (m.z - 10.f) * LOG2E, (m.w - 10.f) * LOG2E };
    ((float4*)mask2)[r] = o;
  }
}

// QKV GEMM. Blocks with n0<1536 write Q/K (Q pre-scaled log2e/8) to OutQK
// [8192][1536]. Blocks with n0>=1536 write V^T directly to Vt [b][h][d][s]
// with the key axis bit2<->bit3 swapped (so flash's PV consumes P in C-layout
// register order with no transform).
__global__ __launch_bounds__(256) void qkv_gemm(
    const unsigned short* __restrict__ Xb,   // [8192][768]
    const unsigned short* __restrict__ Wall, // [2304][768]
    const float* __restrict__ bq,
    const float* __restrict__ bk,
    const float* __restrict__ bv,
    unsigned short* __restrict__ OutQK,      // [8192][1536]
    unsigned short* __restrict__ Vt)         // [48*64][2048], key-bit-swapped
{
  __shared__ __align__(16) short As[128][64];
  __shared__ __align__(16) short Bs[128][64];

  int m0 = blockIdx.y * 128;
  int n0 = blockIdx.x * 128;
  int t = threadIdx.x;
  int w = t >> 6, lane = t & 63, lg = lane >> 4, lc = lane & 15;
  int wr = (w >> 1) * 64, wc = (w & 1) * 64;

  int srow = lane >> 3;
  int schunk = (lane & 7) ^ srow;

  f32x4 acc[4][4] = {};

  for (int k0 = 0; k0 < DMODEL; k0 += 64) {
    __syncthreads();
    for (int it = 0; it < 4; ++it) {
      int rb = w * 32 + it * 8;
      int r = rb + srow;
      gl2lds16(&Xb[(size_t)(m0 + r) * DMODEL + k0 + schunk * 8], &As[rb][0]);
      gl2lds16(&Wall[(size_t)(n0 + r) * DMODEL + k0 + schunk * 8], &Bs[rb][0]);
    }
    __syncthreads();
    for (int ks = 0; ks < 2; ++ks) {
      short8 a[4], b[4];
      for (int mt = 0; mt < 4; ++mt)
        a[mt] = *(const short8*)&As[wr + mt * 16 + lc][(((ks * 4 + lg) ^ (lc & 7))) * 8];
      for (int nt = 0; nt < 4; ++nt)
        b[nt] = *(const short8*)&Bs[wc + nt * 16 + lc][(((ks * 4 + lg) ^ (lc & 7))) * 8];
      for (int mt = 0; mt < 4; ++mt)
        for (int nt = 0; nt < 4; ++nt)
          acc[mt][nt] = __builtin_amdgcn_mfma_f32_16x16x32_bf16(a[mt], b[nt], acc[mt][nt], 0, 0, 0);
    }
  }

  if (n0 < NQK) {
    // Q/K path
    for (int nt = 0; nt < 4; ++nt) {
      int col = n0 + wc + nt * 16 + lc;
      float bb = (col < 768) ? bq[col] : bk[col - 768];
      float sc = (col < 768) ? (0.125f * LOG2E) : 1.0f;
      for (int mt = 0; mt < 4; ++mt) {
        int row = m0 + wr + mt * 16 + lg * 4;
        for (int i = 0; i < 4; ++i)
          OutQK[(size_t)(row + i) * NQK + col] = f2bf((acc[mt][nt][i] + bb) * sc);
      }
    }
  } else {
    // V path: write V^T, key axis bit2<->bit3 swapped (swap lg bits)
    int lgs = ((lg & 1) << 1) | (lg >> 1);
    int b = m0 >> 11;                     // batch (128 | 2048)
    int sb0 = (m0 & 2047) + wr;
    for (int nt = 0; nt < 4; ++nt) {
      int hd = n0 + wc + nt * 16 + lc - NQK;  // 0..767
      int h = hd >> 6, d = hd & 63;
      float bb = bv[hd];
      size_t obase = ((size_t)((b * NH + h) * DHEAD + d)) * S_LEN;
      for (int mt = 0; mt < 4; ++mt) {
        int sb = sb0 + mt * 16 + lgs * 4;
        uint2 u;
        u.x = pack2bf(acc[mt][nt][0] + bb, acc[mt][nt][1] + bb);
        u.y = pack2bf(acc[mt][nt][2] + bb, acc[mt][nt][3] + bb);
        *(uint2*)&Vt[obase + sb] = u;
      }
    }
  }
}

// Flash attention: 32x32x16 MFMA, fixed-max softmax (exp2 domain), key-permuted
// V so P feeds PV directly from registers. Double-buffered K/V (static arrays),
// 1 barrier per 64-key tile. Block = (128 q, h, b); 4 waves x 32 q.
__global__ __launch_bounds__(256, 3) void flash_attn(
    const unsigned short* __restrict__ QK,   // [8192][1536]; Q pre-scaled log2e/8
    const unsigned short* __restrict__ Vt,   // [48*64][2048], key-bit-swapped
    const float* __restrict__ mask2,         // (mask-10)*log2e, [B][S]
    float* __restrict__ out)                 // [B][S][768]
{
  int qt = blockIdx.x, h = blockIdx.y, b = blockIdx.z;
  __shared__ __align__(16) short Ks0[64][64], Vs0[64][64];
  __shared__ __align__(16) short Ks1[64][64], Vs1[64][64];

  int t = threadIdx.x, w = t >> 6, lane = t & 63;
  int m31 = lane & 31, hf = lane >> 5;
  int q0 = qt * 128;
  int srow = lane >> 3;
  int schunk = (lane & 7) ^ srow;

  size_t vtbase = (size_t)((b * NH + h) * DHEAD) * S_LEN;
  const float* mrow = mask2 + (size_t)b * S_LEN;
  size_t kbase0 = (size_t)(b * S_LEN) * NQK + 768 + h * DHEAD;

  // Q B-frags: loop-invariant, direct from global. B[n=q=m31][k=d=16kk+8hf+j]
  short8 qf[4];
  {
    size_t qrow = (size_t)(b * S_LEN + q0 + w * 32 + m31) * NQK + h * DHEAD;
    for (int kk = 0; kk < 4; ++kk)
      qf[kk] = *(const short8*)&QK[qrow + kk * 16 + hf * 8];
  }

  float lsum = 0.f;
  f32x16 o[2] = {};

  int rb0 = w * 16, rb1 = w * 16 + 8;
  int r0 = rb0 + srow, r1 = rb1 + srow;

  // prolog: stage tile 0 into buffer 0
  gl2lds16(&QK[kbase0 + (size_t)r0 * NQK + schunk * 8], &Ks0[rb0][0]);
  gl2lds16(&QK[kbase0 + (size_t)r1 * NQK + schunk * 8], &Ks0[rb1][0]);
  gl2lds16(&Vt[vtbase + (size_t)r0 * S_LEN + schunk * 8], &Vs0[rb0][0]);
  gl2lds16(&Vt[vtbase + (size_t)r1 * S_LEN + schunk * 8], &Vs0[rb1][0]);

  auto body = [&](auto& Kc, auto& Vc, auto& Kn, auto& Vn, int kt) {
    int k0 = kt * 64;
    __syncthreads();  // drains DMA for tile kt; all waves done reading Kn/Vn's old tile

    // prefetch tile kt+1 into the other buffer (overlaps all compute below)
    if (kt + 1 < S_LEN / 64) {
      int k1 = k0 + 64;
      gl2lds16(&QK[kbase0 + (size_t)(k1 + r0) * NQK + schunk * 8], &Kn[rb0][0]);
      gl2lds16(&QK[kbase0 + (size_t)(k1 + r1) * NQK + schunk * 8], &Kn[rb1][0]);
      gl2lds16(&Vt[vtbase + (size_t)r0 * S_LEN + k1 + schunk * 8], &Vn[rb0][0]);
      gl2lds16(&Vt[vtbase + (size_t)r1 * S_LEN + k1 + schunk * 8], &Vn[rb1][0]);
    }

    // S^T[key][q] = K·Q^T: A = K rows, B = qf
    f32x16 s[2] = {};
    for (int kk = 0; kk < 4; ++kk)
      for (int mt = 0; mt < 2; ++mt) {
        int r = mt * 32 + m31;
        short8 ak = *(const short8*)&Kc[r][((kk * 2 + hf) ^ (r & 7)) * 8];
        s[mt] = __builtin_amdgcn_mfma_f32_32x32x16_bf16(ak, qf[kk], s[mt], 0, 0, 0);
      }

    // p = exp2(s + mask2); phys key = 32mt+8g+4hf+(i); q = m31
    unsigned int pk[16];
    for (int mt = 0; mt < 2; ++mt)
      for (int g = 0; g < 4; ++g) {
        float4 mv = *(const float4*)&mrow[k0 + mt * 32 + g * 8 + hf * 4];
        float p0 = exp2f(s[mt][g * 4 + 0] + mv.x);
        float p1 = exp2f(s[mt][g * 4 + 1] + mv.y);
        float p2 = exp2f(s[mt][g * 4 + 2] + mv.z);
        float p3 = exp2f(s[mt][g * 4 + 3] + mv.w);
        lsum += (p0 + p1) + (p2 + p3);
        pk[mt * 8 + g * 2 + 0] = pack2bf(p0, p1);
        pk[mt * 8 + g * 2 + 1] = pack2bf(p2, p3);
      }

    // O += P·V: A-frag kk = pk[4kk..4kk+3] directly (V key axis pre-permuted)
    for (int kk = 0; kk < 4; ++kk) {
      union { unsigned int u[4]; short8 s8; } af;
      af.u[0] = pk[kk * 4 + 0]; af.u[1] = pk[kk * 4 + 1];
      af.u[2] = pk[kk * 4 + 2]; af.u[3] = pk[kk * 4 + 3];
      for (int nt = 0; nt < 2; ++nt) {
        int r = nt * 32 + m31;
        short8 bv = *(const short8*)&Vc[r][((kk * 2 + hf) ^ (r & 7)) * 8];
        o[nt] = __builtin_amdgcn_mfma_f32_32x32x16_bf16(af.s8, bv, o[nt], 0, 0, 0);
      }
    }
  };

  for (int kt = 0; kt < S_LEN / 64; kt += 2) {
    body(Ks0, Vs0, Ks1, Vs1, kt);
    body(Ks1, Vs1, Ks0, Vs0, kt + 1);
  }

  // final l for q=m31: own 32 keys + partner's 32
  lsum += __shfl_xor(lsum, 32, 64);
  float inv = 1.0f / lsum;
  float lv[16];
  for (int r = 0; r < 16; ++r)
    lv[r] = __shfl(inv, (r & 3) + 8 * (r >> 2) + 4 * hf, 64);

  for (int nt = 0; nt < 2; ++nt)
    for (int r = 0; r < 16; ++r) {
      int qrow = (r & 3) + 8 * (r >> 2) + 4 * hf;
      int q = q0 + w * 32 + qrow;
      out[(size_t)(b * S_LEN + q) * DMODEL + h * DHEAD + nt * 32 + m31] = o[nt][r] * lv[r];
    }
}

extern "C" void kernel_launch(void* const* d_in, const int* in_sizes, int n_in,
                              void* d_out, int out_size, void* d_ws, size_t ws_size,
                              hipStream_t stream) {
  const float* hs   = (const float*)d_in[0];
  const float* mask = (const float*)d_in[1];
  const float* Wq   = (const float*)d_in[2];
  const float* bq   = (const float*)d_in[3];
  const float* Wk   = (const float*)d_in[4];
  const float* bk   = (const float*)d_in[5];
  const float* Wv   = (const float*)d_in[6];
  const float* bv   = (const float*)d_in[7];
  float* out = (float*)d_out;

  char* ws = (char*)d_ws;
  const size_t XB_BYTES   = (size_t)MROWS * DMODEL * 2;   // 12.58 MB
  const size_t QK_BYTES   = (size_t)MROWS * NQK * 2;      // 25.17 MB
  const size_t VT_BYTES   = (size_t)MROWS * DMODEL * 2;   // 12.58 MB
  const size_t WALL_BYTES = (size_t)3 * DMODEL * DMODEL * 2;
  unsigned short* Xb    = (unsigned short*)ws;
  unsigned short* QK    = (unsigned short*)(ws + XB_BYTES);
  unsigned short* Vtg   = (unsigned short*)(ws + XB_BYTES + QK_BYTES);
  unsigned short* Wall  = (unsigned short*)(ws + XB_BYTES + QK_BYTES + VT_BYTES);
  float*          mask2 = (float*)(ws + XB_BYTES + QK_BYTES + VT_BYTES + WALL_BYTES);

  const int NX = MROWS * DMODEL / 4;
  const int NW = DMODEL * DMODEL / 4;
  const int NM = (BATCH * S_LEN) / 4;
  int nprep = NX + 3 * NW + NM;
  prep_kernel<<<(nprep + 255) / 256, 256, 0, stream>>>(hs, Wq, Wk, Wv, mask, Xb, Wall, mask2);

  qkv_gemm<<<dim3(2304 / 128, MROWS / 128), 256, 0, stream>>>(Xb, Wall, bq, bk, bv, QK, Vtg);

  flash_attn<<<dim3(S_LEN / 128, NH, BATCH), 256, 0, stream>>>(QK, Vtg, mask2, out);
}